// Round 2
// baseline (110.356 us; speedup 1.0000x reference)
//
#include <hip/hip_runtime.h>
#include <math.h>

#define BATCHN 4096
#define DMODEL 1024
#define NT 64
#define RANK 8
#define K2 512   // NT*RANK

typedef __attribute__((ext_vector_type(8))) short bf16x8;
typedef __attribute__((ext_vector_type(4))) float f32x4;

__device__ __forceinline__ void async16(void* lds, const void* g) {
    __builtin_amdgcn_global_load_lds(
        (const __attribute__((address_space(1))) void*)g,
        (__attribute__((address_space(3))) void*)lds, 16, 0, 0);
}

__device__ __forceinline__ short f2bf(float f) {
    unsigned u = __builtin_bit_cast(unsigned, f);
    u += 0x7fffu + ((u >> 16) & 1u);   // round-to-nearest-even
    return (short)(u >> 16);
}

// ---- convert: fp32 -> bf16 for x, [enc;V], U(native [n][d][r]) + sumsq partials.
// 648 blocks x 256 thr, each thread handles 32 elems (4 coalesced sweeps of 8).
// Blocks 512..519: enc rows. 520..583: V_n (one n per block) -> sv_part[n].
// Blocks 584..647: U_n (one n per block) -> su_part[n].
__global__ __launch_bounds__(256) void convert_kernel(
    const float* __restrict__ x, const float* __restrict__ enc,
    const float* __restrict__ V, const float* __restrict__ U,
    unsigned short* __restrict__ xb, unsigned short* __restrict__ Wb,
    unsigned short* __restrict__ Ub,
    float* __restrict__ su_part, float* __restrict__ sv_part)
{
    const int b = blockIdx.x, t = threadIdx.x;
    float s = 0.f;
    float* psum = nullptr;

    if (b < 512) {                                // x: 512 * 8192 elems
        const size_t base = (size_t)b * 8192;
        #pragma unroll
        for (int it = 0; it < 4; ++it) {
            const size_t e = base + it * 2048 + t * 8;
            float4 v0 = *(const float4*)(x + e);
            float4 v1 = *(const float4*)(x + e + 4);
            bf16x8 o;
            o[0]=f2bf(v0.x); o[1]=f2bf(v0.y); o[2]=f2bf(v0.z); o[3]=f2bf(v0.w);
            o[4]=f2bf(v1.x); o[5]=f2bf(v1.y); o[6]=f2bf(v1.z); o[7]=f2bf(v1.w);
            *(bf16x8*)(xb + e) = o;
        }
    } else if (b < 584) {                         // W = [enc;V]: 72 * 8192 elems
        const size_t base = (size_t)(b - 512) * 8192;
        const bool isV = (b >= 520);
        if (isV) psum = sv_part + (b - 520);
        #pragma unroll
        for (int it = 0; it < 4; ++it) {
            const size_t e = base + it * 2048 + t * 8;
            const int row = (int)(e >> 10), col = (int)(e & 1023);
            const float* src = (row < 64)
                ? enc + (size_t)row * 1024 + col
                : V + (size_t)(row - 64) * 1024 + col;
            float4 v0 = *(const float4*)src;
            float4 v1 = *(const float4*)(src + 4);
            bf16x8 o;
            o[0]=f2bf(v0.x); o[1]=f2bf(v0.y); o[2]=f2bf(v0.z); o[3]=f2bf(v0.w);
            o[4]=f2bf(v1.x); o[5]=f2bf(v1.y); o[6]=f2bf(v1.z); o[7]=f2bf(v1.w);
            *(bf16x8*)(Wb + e) = o;
            if (isV)
                s += v0.x*v0.x + v0.y*v0.y + v0.z*v0.z + v0.w*v0.w
                   + v1.x*v1.x + v1.y*v1.y + v1.z*v1.z + v1.w*v1.w;
        }
    } else {                                      // U native: 64 * 8192 elems
        const int n = b - 584;
        psum = su_part + n;
        const size_t base = (size_t)n * 8192;
        #pragma unroll
        for (int it = 0; it < 4; ++it) {
            const size_t e = base + it * 2048 + t * 8;
            float4 v0 = *(const float4*)(U + e);
            float4 v1 = *(const float4*)(U + e + 4);
            bf16x8 o;
            o[0]=f2bf(v0.x); o[1]=f2bf(v0.y); o[2]=f2bf(v0.z); o[3]=f2bf(v0.w);
            o[4]=f2bf(v1.x); o[5]=f2bf(v1.y); o[6]=f2bf(v1.z); o[7]=f2bf(v1.w);
            *(bf16x8*)(Ub + e) = o;
            s += v0.x*v0.x + v0.y*v0.y + v0.z*v0.z + v0.w*v0.w
               + v1.x*v1.x + v1.y*v1.y + v1.z*v1.z + v1.w*v1.w;
        }
    }

    if (psum) {
        #pragma unroll
        for (int off = 32; off; off >>= 1) s += __shfl_down(s, off);
        __shared__ float red[4];
        if ((t & 63) == 0) red[t >> 6] = s;
        __syncthreads();
        if (t == 0) *psum = red[0] + red[1] + red[2] + red[3];
    }
}

// ---- K1: merged gate + raw-vx GEMM. C = xb @ Wb^T. grid (9,64), BM=64 BN=64 BK=64.
// Double-buffered 2-phase pipeline. Epilogue stages C in LDS for coalesced stores:
// bn==0: gate = relu(C - bias) fp32 (f32x4 stores); bn>=1: vx = bf16(C) (bf16x8 stores).
__global__ __launch_bounds__(256) void gatevx_kernel(
    const unsigned short* __restrict__ A, const unsigned short* __restrict__ Bm,
    const float* __restrict__ bias,
    float* __restrict__ gate_out, unsigned short* __restrict__ vx_out)
{
    constexpr int BK = 64, KDIM = DMODEL, NIT = KDIM / BK;  // 16 iters
    __shared__ unsigned short As[2][64 * BK];   // 16 KB total (also C staging)
    __shared__ unsigned short Bs[2][64 * BK];
    const int t = threadIdx.x;
    const int wave = t >> 6, lane = t & 63;
    const int bm = blockIdx.y, bn = blockIdx.x;
    const int wm = wave & 1, wn = wave >> 1;
    const int lrow = lane >> 3, lchunk = lane & 7;
    const int l15 = lane & 15, lq = lane >> 4;

    f32x4 acc[2][2] = {};
    const size_t Abase = (size_t)bm * 64 * KDIM;
    const size_t Bbase = (size_t)bn * 64 * KDIM;

    auto STAGE = [&](int buf, int k0) {
        #pragma unroll
        for (int c = 0; c < 2; ++c) {
            const int row = (wave * 2 + c) * 8 + lrow;
            const int chunk = lchunk ^ lrow;
            async16(&As[buf][(wave * 2 + c) * 512],
                    A + Abase + (size_t)row * KDIM + k0 + chunk * 8);
            async16(&Bs[buf][(wave * 2 + c) * 512],
                    Bm + Bbase + (size_t)row * KDIM + k0 + chunk * 8);
        }
    };
    auto COMPUTE = [&](int buf) {
        #pragma unroll
        for (int s = 0; s < 2; ++s) {
            bf16x8 af[2], bfr[2];
            const int kc = s * 4 + lq;
            #pragma unroll
            for (int i = 0; i < 2; ++i) {
                const int m = wm * 32 + i * 16 + l15;
                af[i] = *(const bf16x8*)&As[buf][m * BK + ((kc ^ (m & 7)) * 8)];
            }
            #pragma unroll
            for (int j = 0; j < 2; ++j) {
                const int n = wn * 32 + j * 16 + l15;
                bfr[j] = *(const bf16x8*)&Bs[buf][n * BK + ((kc ^ (n & 7)) * 8)];
            }
            #pragma unroll
            for (int i = 0; i < 2; ++i)
                #pragma unroll
                for (int j = 0; j < 2; ++j)
                    acc[i][j] = __builtin_amdgcn_mfma_f32_16x16x32_bf16(
                        af[i], bfr[j], acc[i][j], 0, 0, 0);
        }
    };

    STAGE(0, 0);
    __syncthreads();
    int cur = 0;
    for (int kt = 0; kt < NIT - 1; ++kt) {
        STAGE(cur ^ 1, (kt + 1) * BK);
        COMPUTE(cur);
        __syncthreads();
        cur ^= 1;
    }
    COMPUTE(cur);
    __syncthreads();                 // done reading LDS; reuse As as C staging

    if (bn == 0) {
        float* Cs = (float*)&As[0][0];           // 64x64 f32 = 16 KB
        #pragma unroll
        for (int i = 0; i < 2; ++i) {
            const int rowb = wm * 32 + i * 16 + lq * 4;
            #pragma unroll
            for (int j = 0; j < 2; ++j) {
                const int col = wn * 32 + j * 16 + l15;
                const float bz = bias[col];
                #pragma unroll
                for (int r = 0; r < 4; ++r) {
                    const float p = acc[i][j][r] - bz;
                    Cs[(rowb + r) * 64 + col] = p > 0.f ? p : 0.f;
                }
            }
        }
        __syncthreads();
        #pragma unroll
        for (int p = 0; p < 4; ++p) {            // 256B-contiguous rows
            const int row = p * 16 + (t >> 4);
            const int col = (t & 15) * 4;
            *(f32x4*)&gate_out[(size_t)(bm * 64 + row) * NT + col] =
                *(const f32x4*)&Cs[row * 64 + col];
        }
    } else {
        unsigned short* Cs16 = &As[0][0];        // 64x64 bf16 = 8 KB
        #pragma unroll
        for (int i = 0; i < 2; ++i) {
            const int rowb = wm * 32 + i * 16 + lq * 4;
            #pragma unroll
            for (int j = 0; j < 2; ++j) {
                const int col = wn * 32 + j * 16 + l15;
                #pragma unroll
                for (int r = 0; r < 4; ++r)
                    Cs16[(rowb + r) * 64 + col] = (unsigned short)f2bf(acc[i][j][r]);
            }
        }
        __syncthreads();
        #pragma unroll
        for (int p = 0; p < 2; ++p) {            // 128B-contiguous row chunks
            const int row = p * 32 + (t >> 3);
            const int chunk = t & 7;
            *(bf16x8*)&vx_out[(size_t)(bm * 64 + row) * K2 + (bn - 1) * 64 + chunk * 8] =
                *(const bf16x8*)&Cs16[row * 64 + chunk * 8];
        }
    }
}

// ---- K2: out = (gate ⊙ vx) @ U^T (U native [n][d][r] bf16). grid (8,64),
// BM=64 BN=128 BK=64, KDIM=512. Gating folded into A-staging; T14 split.
// Epilogue stages C (64x128 f32, 32KB in Bs) for 512B-coalesced out stores.
__global__ __launch_bounds__(256) void out_kernel(
    const unsigned short* __restrict__ vx, const float* __restrict__ gate,
    const unsigned short* __restrict__ Ub, float* __restrict__ out,
    const float* __restrict__ su_part, const float* __restrict__ sv_part,
    float* __restrict__ fro)
{
    constexpr int BK = 64, KDIM = K2, NIT = KDIM / BK;   // 8 iters
    __shared__ unsigned short As[2][64 * BK];            // 16 KB
    __shared__ unsigned short Bs[2][8 * 2 * 64 * 8];     // 32 KB (also C staging)
    const int t = threadIdx.x;
    const int wave = t >> 6, lane = t & 63;
    const int bm = blockIdx.y, bn = blockIdx.x;
    const int wm = wave & 1, wn = wave >> 1;
    const int lrow = lane >> 3, lchunk = lane & 7;
    const int l15 = lane & 15, lq = lane >> 4;

    f32x4 acc[2][4] = {};

    auto LOADA = [&](int k0, bf16x8* v, float* g) {
        #pragma unroll
        for (int c = 0; c < 2; ++c) {
            const int row = (wave * 2 + c) * 8 + lrow;
            const int grow = bm * 64 + row;
            const int chunk = lchunk ^ lrow;
            v[c] = *(const bf16x8*)(vx + (size_t)grow * K2 + k0 + chunk * 8);
            g[c] = gate[(size_t)grow * NT + (k0 >> 3) + chunk];
        }
    };
    auto WRITEA = [&](int buf, const bf16x8* v, const float* g) {
        #pragma unroll
        for (int c = 0; c < 2; ++c) {
            bf16x8 o;
            #pragma unroll
            for (int e = 0; e < 8; ++e) {
                const float f = __builtin_bit_cast(float,
                    ((unsigned)(unsigned short)v[c][e]) << 16);
                o[e] = (short)(__builtin_bit_cast(unsigned, f * g[c]) >> 16);  // trunc
            }
            *(bf16x8*)&As[buf][(wave * 2 + c) * 512 + lane * 8] = o;
        }
    };
    auto STAGEB = [&](int buf, int k0) {
        #pragma unroll
        for (int c = 0; c < 4; ++c) {
            const int n_local = wave * 2 + (c >> 1);
            const int dblk = c & 1;
            const int n_glob = (k0 >> 3) + n_local;
            async16(&Bs[buf][(n_local * 2 + dblk) * 512],
                    Ub + (size_t)n_glob * (DMODEL * RANK)
                       + (size_t)(bn * 128 + dblk * 64 + lane) * RANK);
        }
    };
    auto COMPUTE = [&](int buf) {
        #pragma unroll
        for (int s = 0; s < 2; ++s) {
            bf16x8 af[2], bfr[4];
            const int kc = s * 4 + lq;   // = n_local
            #pragma unroll
            for (int i = 0; i < 2; ++i) {
                const int m = wm * 32 + i * 16 + l15;
                af[i] = *(const bf16x8*)&As[buf][m * BK + ((kc ^ (m & 7)) * 8)];
            }
            #pragma unroll
            for (int j = 0; j < 4; ++j) {
                const int cl = wn * 64 + j * 16 + l15;
                bfr[j] = *(const bf16x8*)&Bs[buf][((kc * 2 + (cl >> 6)) * 64 + (cl & 63)) * 8];
            }
            #pragma unroll
            for (int i = 0; i < 2; ++i)
                #pragma unroll
                for (int j = 0; j < 4; ++j)
                    acc[i][j] = __builtin_amdgcn_mfma_f32_16x16x32_bf16(
                        af[i], bfr[j], acc[i][j], 0, 0, 0);
        }
    };

    {   // prologue
        bf16x8 v[2]; float g[2];
        LOADA(0, v, g);
        STAGEB(0, 0);
        WRITEA(0, v, g);
    }
    __syncthreads();
    int cur = 0;
    for (int kt = 0; kt < NIT - 1; ++kt) {
        bf16x8 v[2]; float g[2];
        LOADA((kt + 1) * BK, v, g);
        STAGEB(cur ^ 1, (kt + 1) * BK);
        COMPUTE(cur);
        WRITEA(cur ^ 1, v, g);
        __syncthreads();
        cur ^= 1;
    }
    COMPUTE(cur);
    __syncthreads();                 // done reading LDS; reuse Bs as C staging

    float* Cs = (float*)&Bs[0][0];   // 64x128 f32 = 32 KB
    #pragma unroll
    for (int i = 0; i < 2; ++i) {
        const int rowb = wm * 32 + i * 16 + lq * 4;
        #pragma unroll
        for (int j = 0; j < 4; ++j) {
            const int col = wn * 64 + j * 16 + l15;
            #pragma unroll
            for (int r = 0; r < 4; ++r)
                Cs[(rowb + r) * 128 + col] = acc[i][j][r];
        }
    }
    __syncthreads();
    #pragma unroll
    for (int p = 0; p < 8; ++p) {    // 512B-contiguous rows
        const int row = p * 8 + (t >> 5);
        const int col = (t & 31) * 4;
        *(f32x4*)&out[(size_t)(bm * 64 + row) * DMODEL + bn * 128 + col] =
            *(const f32x4*)&Cs[row * 128 + col];
    }

    // finalize Frobenius norms (convert_kernel ran before us in-stream)
    if (bn == 0 && bm == 0 && t < NT) {
        fro[t] = sqrtf(su_part[t]) * sqrtf(sv_part[t]) / sqrtf((float)(DMODEL * RANK));
    }
}

extern "C" void kernel_launch(void* const* d_in, const int* in_sizes, int n_in,
                              void* d_out, int out_size, void* d_ws, size_t ws_size,
                              hipStream_t stream) {
    const float* x    = (const float*)d_in[0];
    const float* V    = (const float*)d_in[1];
    const float* U    = (const float*)d_in[2];
    const float* enc  = (const float*)d_in[3];
    const float* bias = (const float*)d_in[4];

    float* out  = (float*)d_out;                       // [4096,1024]
    float* gate = out + (size_t)BATCHN * DMODEL;       // [4096,64] fp32
    float* fro  = gate + (size_t)BATCHN * NT;          // [64]

    char* ws = (char*)d_ws;
    unsigned short* xb = (unsigned short*)ws;                    // 8,388,608 B
    unsigned short* Wb = (unsigned short*)(ws + 8388608);        // 1,179,648 B
    unsigned short* Ub = (unsigned short*)(ws + 9568256);        // 1,048,576 B
    unsigned short* vx = (unsigned short*)(ws + 10616832);       // 4,194,304 B
    float* su_part     = (float*)(ws + 14811136);                // 256 B
    float* sv_part     = (float*)(ws + 14812160);                // 256 B

    convert_kernel<<<648, 256, 0, stream>>>(x, enc, V, U, xb, Wb, Ub, su_part, sv_part);
    gatevx_kernel<<<dim3(9, 64), 256, 0, stream>>>(xb, Wb, bias, gate, vx);
    out_kernel<<<dim3(8, 64), 256, 0, stream>>>(vx, gate, Ub, out, su_part, sv_part, fro);
}